// Round 1
// baseline (578.143 us; speedup 1.0000x reference)
//
#include <hip/hip_runtime.h>
#include <hip/hip_bf16.h>

#define DDIM 64

using bf16x8 = __attribute__((ext_vector_type(8))) short;
using f32x4  = __attribute__((ext_vector_type(4))) float;

__device__ inline unsigned short f2bf(float f) {
  union { float f; unsigned u; } v; v.f = f;
  unsigned u = v.u + 0x7fffu + ((v.u >> 16) & 1u);  // RNE
  return (unsigned short)(u >> 16);
}
__device__ inline float bf2f(unsigned short h) {
  union { float f; unsigned u; } v; v.u = ((unsigned)h) << 16; return v.f;
}

// Convert fp32 rows -> bf16 rows, compute per-row sum of squares (of the
// bf16-rounded values, so the GEMM identity is exact for the rounded vectors).
// 16 lanes per row, 4 elems (one float4) per lane.
__global__ __launch_bounds__(256) void prep_kernel(
    const float* __restrict__ x, const float* __restrict__ y,
    unsigned short* __restrict__ xb, unsigned short* __restrict__ yb,
    float* __restrict__ xn, float* __restrict__ yn, int M, int N) {
  int tid = threadIdx.x;
  int row = blockIdx.x * 16 + (tid >> 4);
  int l   = tid & 15;
  const float* src; unsigned short* dst; float* nrm;
  if (row < M) {
    src = x + (size_t)row * DDIM; dst = xb + (size_t)row * DDIM; nrm = xn + row;
  } else {
    int r = row - M;
    if (r >= N) return;
    src = y + (size_t)r * DDIM; dst = yb + (size_t)r * DDIM; nrm = yn + r;
  }
  float4 v = *(const float4*)(src + l * 4);
  unsigned short b0 = f2bf(v.x), b1 = f2bf(v.y), b2 = f2bf(v.z), b3 = f2bf(v.w);
  float f0 = bf2f(b0), f1 = bf2f(b1), f2 = bf2f(b2), f3 = bf2f(b3);
  ushort4 s; s.x = b0; s.y = b1; s.z = b2; s.w = b3;
  *(ushort4*)(dst + l * 4) = s;
  float acc = f0 * f0 + f1 * f1 + f2 * f2 + f3 * f3;
  #pragma unroll
  for (int m = 1; m < 16; m <<= 1) acc += __shfl_xor(acc, m, 16);
  if (l == 0) *nrm = acc;
}

// One block = 128x128 output tile, 4 waves in 2x2, each wave 64x64 via
// 4x4 grid of 16x16x32 bf16 MFMAs, K=64 in two k-steps. No LDS: A/B
// fragment layouts (elem[lane&15][quad*8+j]) match row-major K-contiguous
// storage directly; data footprint (3 MiB) lives in L2.
__global__ __launch_bounds__(256) void cdist_mfma_kernel(
    const unsigned short* __restrict__ xb, const unsigned short* __restrict__ yb,
    const float* __restrict__ xn, const float* __restrict__ yn,
    float* __restrict__ out, int Ncols) {
  int mbase = blockIdx.y * 128, nbase = blockIdx.x * 128;
  int tid = threadIdx.x, wave = tid >> 6, lane = tid & 63;
  int quad = lane >> 4, l16 = lane & 15;
  int wm = (wave >> 1) * 64, wn = (wave & 1) * 64;

  const short* xp = (const short*)xb;
  const short* yp = (const short*)yb;
  int arow = mbase + wm + l16;
  int brow = nbase + wn + l16;
  int koff = quad * 8;

  bf16x8 a[2][4], b[2][4];
  #pragma unroll
  for (int i = 0; i < 4; i++) {
    const short* ap = xp + (size_t)(arow + i * 16) * DDIM + koff;
    const short* bp = yp + (size_t)(brow + i * 16) * DDIM + koff;
    a[0][i] = *(const bf16x8*)(ap);
    a[1][i] = *(const bf16x8*)(ap + 32);
    b[0][i] = *(const bf16x8*)(bp);
    b[1][i] = *(const bf16x8*)(bp + 32);
  }

  f32x4 acc[4][4] = {};
  #pragma unroll
  for (int ks = 0; ks < 2; ks++)
    #pragma unroll
    for (int i = 0; i < 4; i++)
      #pragma unroll
      for (int j = 0; j < 4; j++)
        acc[i][j] = __builtin_amdgcn_mfma_f32_16x16x32_bf16(
            a[ks][i], b[ks][j], acc[i][j], 0, 0, 0);

  // Epilogue: d = sqrt(max(xn + yn - 2*dot, 0)). C/D layout: col=lane&15,
  // row=quad*4+reg.
  #pragma unroll
  for (int i = 0; i < 4; i++) {
    int r0 = mbase + wm + i * 16 + quad * 4;
    float xnv[4];
    #pragma unroll
    for (int r = 0; r < 4; r++) xnv[r] = xn[r0 + r];
    #pragma unroll
    for (int j = 0; j < 4; j++) {
      int col = nbase + wn + j * 16 + l16;
      float ynv = yn[col];
      #pragma unroll
      for (int r = 0; r < 4; r++) {
        float d2 = xnv[r] + ynv - 2.0f * acc[i][j][r];
        out[(size_t)(r0 + r) * Ncols + col] = sqrtf(fmaxf(d2, 0.0f));
      }
    }
  }
}

// Correctness fallback if workspace is too small (shouldn't happen).
__global__ void cdist_naive_kernel(const float* __restrict__ x,
                                   const float* __restrict__ y,
                                   float* __restrict__ out, int M, int N) {
  size_t idx = (size_t)blockIdx.x * blockDim.x + threadIdx.x;
  size_t total = (size_t)M * N;
  if (idx >= total) return;
  int i = (int)(idx / N), j = (int)(idx % N);
  const float* xi = x + (size_t)i * DDIM;
  const float* yj = y + (size_t)j * DDIM;
  float acc = 0.f;
  #pragma unroll
  for (int k = 0; k < DDIM; k++) {
    float d = xi[k] - yj[k];
    acc += d * d;
  }
  out[idx] = sqrtf(acc);
}

extern "C" void kernel_launch(void* const* d_in, const int* in_sizes, int n_in,
                              void* d_out, int out_size, void* d_ws, size_t ws_size,
                              hipStream_t stream) {
  const float* x = (const float*)d_in[0];
  const float* y = (const float*)d_in[1];
  float* out = (float*)d_out;
  int M = in_sizes[0] / DDIM;   // 8192
  int N = in_sizes[1] / DDIM;   // 16384

  size_t xb_off = 0;
  size_t yb_off = xb_off + (size_t)M * DDIM * sizeof(unsigned short);
  size_t xn_off = yb_off + (size_t)N * DDIM * sizeof(unsigned short);
  size_t yn_off = xn_off + (size_t)M * sizeof(float);
  size_t need   = yn_off + (size_t)N * sizeof(float);

  if (ws_size < need || (M % 128) || (N % 128)) {
    size_t total = (size_t)M * N;
    int blocks = (int)((total + 255) / 256);
    cdist_naive_kernel<<<blocks, 256, 0, stream>>>(x, y, out, M, N);
    return;
  }

  unsigned short* xb = (unsigned short*)((char*)d_ws + xb_off);
  unsigned short* yb = (unsigned short*)((char*)d_ws + yb_off);
  float* xn = (float*)((char*)d_ws + xn_off);
  float* yn = (float*)((char*)d_ws + yn_off);

  int prep_blocks = (M + N) / 16;
  prep_kernel<<<prep_blocks, 256, 0, stream>>>(x, y, xb, yb, xn, yn, M, N);

  dim3 grid(N / 128, M / 128);
  cdist_mfma_kernel<<<grid, 256, 0, stream>>>(xb, yb, xn, yn, out, N);
}